// Round 1
// baseline (332.329 us; speedup 1.0000x reference)
//
#include <hip/hip_runtime.h>

// ROI pooling (bilinear crop-and-resize to 9x9), TF2 half-pixel semantics.
// feature_map: [B=4, H=256, W=256, C=256] f32 (NHWC, channels contiguous)
// rois:        [B, R=128, 4] int32 = (x, y, w, h)
// out:         [B, R, 9, 9, C] f32
//
// One wave (64 lanes) per pooling cell; lane handles 4 channels via float4.
// All index math is wave-uniform; 4 corner loads are each one coalesced
// 1 KB transaction.

#define PH 9
#define PW 9

__global__ __launch_bounds__(256) void roi_pool_kernel(
    const float* __restrict__ fm,    // [B,H,W,C]
    const int*   __restrict__ rois,  // [B,R,4]
    float*       __restrict__ out,   // [B,R,PH,PW,C]
    int B, int H, int W, int C, int R)
{
    const int lane = threadIdx.x & 63;
    const int wave = threadIdx.x >> 6;
    const int cell = blockIdx.x * 4 + wave;   // 4 waves per block
    const int ncells = B * R * PH * PW;
    if (cell >= ncells) return;

    // cell = ((b*R + r)*PH + py)*PW + px
    int px = cell % PW;
    int t  = cell / PW;
    int py = t % PH;
    t /= PH;
    const int r = t % R;
    const int b = t / R;

    const int* roi = rois + (b * R + r) * 4;
    const int rx = roi[0];
    const int ry = roi[1];
    const int rw = roi[2];
    const int rh = roi[3];

    const float hf = (float)rh;
    const float wf = (float)rw;

    // sy = (py+0.5) * (h/PH) - 0.5, clamped to [0, h-1]  (match reference op order)
    float sy = ((float)py + 0.5f) * (hf / (float)PH) - 0.5f;
    float sx = ((float)px + 0.5f) * (wf / (float)PW) - 0.5f;
    sy = fminf(fmaxf(sy, 0.0f), hf - 1.0f);
    sx = fminf(fmaxf(sx, 0.0f), wf - 1.0f);

    const float y0f = floorf(sy);
    const float x0f = floorf(sx);
    const float fy = sy - y0f;
    const float fx = sx - x0f;
    const int y0 = (int)y0f;
    const int x0 = (int)x0f;
    const int y1 = min(y0 + 1, rh - 1);
    const int x1 = min(x0 + 1, rw - 1);

    const long ya0 = (long)ry + y0;
    const long ya1 = (long)ry + y1;
    const long xa0 = (long)rx + x0;
    const long xa1 = (long)rx + x1;

    const long base_b = (long)b * H;
    const float4* p00 = (const float4*)(fm + ((base_b + ya0) * W + xa0) * C) + lane;
    const float4* p01 = (const float4*)(fm + ((base_b + ya0) * W + xa1) * C) + lane;
    const float4* p10 = (const float4*)(fm + ((base_b + ya1) * W + xa0) * C) + lane;
    const float4* p11 = (const float4*)(fm + ((base_b + ya1) * W + xa1) * C) + lane;

    const float4 v00 = *p00;
    const float4 v01 = *p01;
    const float4 v10 = *p10;
    const float4 v11 = *p11;

    const float gx = 1.0f - fx;
    const float gy = 1.0f - fy;

    // top = v0*(1-fx) + v1*fx ; bot likewise ; out = top*(1-fy) + bot*fy
    float4 o;
    o.x = (v00.x * gx + v01.x * fx) * gy + (v10.x * gx + v11.x * fx) * fy;
    o.y = (v00.y * gx + v01.y * fx) * gy + (v10.y * gx + v11.y * fx) * fy;
    o.z = (v00.z * gx + v01.z * fx) * gy + (v10.z * gx + v11.z * fx) * fy;
    o.w = (v00.w * gx + v01.w * fx) * gy + (v10.w * gx + v11.w * fx) * fy;

    float4* po = (float4*)(out + (long)cell * C) + lane;
    *po = o;
}

extern "C" void kernel_launch(void* const* d_in, const int* in_sizes, int n_in,
                              void* d_out, int out_size, void* d_ws, size_t ws_size,
                              hipStream_t stream) {
    const float* fm   = (const float*)d_in[0];
    const int*   rois = (const int*)d_in[1];
    float*       out  = (float*)d_out;

    const int B = 4, H = 256, W = 256, C = 256, R = 128;
    const int ncells = B * R * PH * PW;        // 41472
    const int blocks = (ncells + 3) / 4;       // 4 cells (waves) per 256-thread block

    roi_pool_kernel<<<blocks, 256, 0, stream>>>(fm, rois, out, B, H, W, C, R);
}